// Round 2
// baseline (769.904 us; speedup 1.0000x reference)
//
#include <hip/hip_runtime.h>

// ---------------------------------------------------------------------------
// Problem constants
// ---------------------------------------------------------------------------
#define S_LEN   2048
#define HID     4096
#define NH      32
#define NKV     8
#define HD      128
#define QKV_N   (NH*HD + 2*NKV*HD)   // 6144
#define WINDOW  1024

typedef unsigned short u16;
typedef short s8v  __attribute__((ext_vector_type(8)));
typedef short s4v  __attribute__((ext_vector_type(4)));
typedef float f4v  __attribute__((ext_vector_type(4)));

#define MFMA16x32(a, b, c) __builtin_amdgcn_mfma_f32_16x16x32_bf16(a, b, c, 0, 0, 0)

__device__ __forceinline__ float bf2f(u16 h) {
  union { unsigned int u; float f; } x;
  x.u = ((unsigned int)h) << 16;
  return x.f;
}
__device__ __forceinline__ u16 f2bf(float f) {
  union { float f; unsigned int u; } x;
  x.f = f;
  unsigned int u = x.u;
  return (u16)((u + 0x7FFFu + ((u >> 16) & 1u)) >> 16);
}

// ---------------------------------------------------------------------------
// GEMM: C[M,N] = A[M,K] * B[N,K]^T + bias[N]
// A: f32 (A_BF16=0) or bf16-u16 (A_BF16=1). B,bias: f32. C: f32.
// f32 operands are converted to bf16 while staging into LDS; MFMA bf16.
// 128x128 tile, BK=32. M,N multiples of 128; K multiple of 32.
// ---------------------------------------------------------------------------
template<int A_BF16>
__global__ __launch_bounds__(256) void gemm_t(
    const void* __restrict__ Ap, const float* __restrict__ B,
    const float* __restrict__ bias, float* __restrict__ C,
    int M, int N, int K)
{
  __shared__ __align__(16) u16 sA[128 * 32];
  __shared__ __align__(16) u16 sB[128 * 32];
  const int tid  = threadIdx.x;
  const int lane = tid & 63;
  const int w    = tid >> 6;      // wave 0..3
  const int wr   = w >> 1, wc = w & 1;
  const int ln   = lane & 15, quad = lane >> 4;
  const long mBase = (long)blockIdx.y * 128;
  const long nBase = (long)blockIdx.x * 128;

  f4v acc[4][4];
#pragma unroll
  for (int i = 0; i < 4; ++i)
#pragma unroll
    for (int j = 0; j < 4; ++j)
#pragma unroll
      for (int r = 0; r < 4; ++r) acc[i][j][r] = 0.0f;

  const int steps = K >> 5;
  for (int kt = 0; kt < steps; ++kt) {
    __syncthreads();
    if (A_BF16) {
      const u16* A = (const u16*)Ap;
#pragma unroll
      for (int i = 0; i < 2; ++i) {
        int c = i * 256 + tid;               // 512 chunks of 8 u16
        int row = c >> 2, col = (c & 3) << 3;
        s8v v = *(const s8v*)&A[(mBase + row) * (long)K + kt * 32 + col];
        *(s8v*)&sA[row * 32 + col] = v;
      }
    } else {
      const float* A = (const float*)Ap;
#pragma unroll
      for (int i = 0; i < 4; ++i) {
        int c = i * 256 + tid;               // 1024 chunks of 4 f32
        int row = c >> 3, col = (c & 7) << 2;
        float4 v = *(const float4*)&A[(mBase + row) * (long)K + kt * 32 + col];
        u16 h[4] = { f2bf(v.x), f2bf(v.y), f2bf(v.z), f2bf(v.w) };
        *(s4v*)&sA[row * 32 + col] = *(const s4v*)h;
      }
    }
#pragma unroll
    for (int i = 0; i < 4; ++i) {
      int c = i * 256 + tid;
      int row = c >> 3, col = (c & 7) << 2;
      float4 v = *(const float4*)&B[(nBase + row) * (long)K + kt * 32 + col];
      u16 h[4] = { f2bf(v.x), f2bf(v.y), f2bf(v.z), f2bf(v.w) };
      *(s4v*)&sB[row * 32 + col] = *(const s4v*)h;
    }
    __syncthreads();

    s8v af[4], bfr[4];
#pragma unroll
    for (int i = 0; i < 4; ++i)
      af[i] = *(const s8v*)&sA[(wr * 64 + i * 16 + ln) * 32 + quad * 8];
#pragma unroll
    for (int j = 0; j < 4; ++j)
      bfr[j] = *(const s8v*)&sB[(wc * 64 + j * 16 + ln) * 32 + quad * 8];
#pragma unroll
    for (int i = 0; i < 4; ++i)
#pragma unroll
      for (int j = 0; j < 4; ++j)
        acc[i][j] = MFMA16x32(af[i], bfr[j], acc[i][j]);
  }

  // Epilogue: C row = quad*4 + r, col = ln (per 16x16 tile)
#pragma unroll
  for (int i = 0; i < 4; ++i) {
    long rowb = mBase + wr * 64 + i * 16 + quad * 4;
#pragma unroll
    for (int j = 0; j < 4; ++j) {
      long col = nBase + wc * 64 + j * 16 + ln;
      float bv = bias[col];
#pragma unroll
      for (int r = 0; r < 4; ++r)
        C[(rowb + r) * (long)N + col] = acc[i][j][r] + bv;
    }
  }
}

// ---------------------------------------------------------------------------
// RoPE (YaRN, NEOX) + split qkv -> q,k,v bf16. SCALE folded into q.
// One block per sequence position.
// ---------------------------------------------------------------------------
__global__ __launch_bounds__(256) void rope_split(
    const float* __restrict__ qkv, const int* __restrict__ positions,
    u16* __restrict__ qo, u16* __restrict__ ko, u16* __restrict__ vo)
{
  const int s = blockIdx.x;
  const int t = threadIdx.x;
  __shared__ float csh[64], snh[64];

  if (t < 64) {
    const double LN_BASE = log(500000.0);
    const double TWO_PI  = 6.283185307179586476925287;
    double cf  = 128.0 * log(32768.0 / (32.0 * TWO_PI)) / (2.0 * LN_BASE);
    double cs_ = 128.0 * log(32768.0 / TWO_PI) / (2.0 * LN_BASE);
    double lowd  = floor(cf);  if (lowd < 0.0)  lowd = 0.0;
    double highd = ceil(cs_);  if (highd > 63.0) highd = 63.0;
    double denom = highd - lowd; if (denom < 0.001) denom = 0.001;
    double d = (double)t;
    double inv_extra = exp(-LN_BASE * d / 64.0);
    double inv_inter = inv_extra * 0.25;      // / FACTOR
    double ramp = (d - lowd) / denom;
    ramp = ramp < 0.0 ? 0.0 : (ramp > 1.0 ? 1.0 : ramp);
    double maskv = 1.0 - ramp;
    double invf = inv_inter * (1.0 - maskv) + inv_extra * maskv;
    float freq = (float)positions[s] * (float)invf;
    const float msc = 1.1386294361119891f;    // 0.1*ln(4)+1
    csh[t] = cosf(freq) * msc;
    snh[t] = sinf(freq) * msc;
  }
  __syncthreads();

  const float* row = qkv + (size_t)s * QKV_N;
  const float SC = 0.08838834764831845f;      // 128^-0.5

#pragma unroll
  for (int i = 0; i < 8; ++i) {
    int p = i * 256 + t;
    int hh = p >> 6, d = p & 63;
    float x1 = row[hh * 128 + d], x2 = row[hh * 128 + d + 64];
    float c = csh[d], sn = snh[d];
    qo[(size_t)s * 4096 + hh * 128 + d]      = f2bf((x1 * c - x2 * sn) * SC);
    qo[(size_t)s * 4096 + hh * 128 + d + 64] = f2bf((x2 * c + x1 * sn) * SC);
  }
#pragma unroll
  for (int i = 0; i < 2; ++i) {
    int p = i * 256 + t;
    int hh = p >> 6, d = p & 63;
    float x1 = row[4096 + hh * 128 + d], x2 = row[4096 + hh * 128 + d + 64];
    float c = csh[d], sn = snh[d];
    ko[(size_t)s * 1024 + hh * 128 + d]      = f2bf(x1 * c - x2 * sn);
    ko[(size_t)s * 1024 + hh * 128 + d + 64] = f2bf(x2 * c + x1 * sn);
  }
#pragma unroll
  for (int i = 0; i < 4; ++i) {
    int e = i * 256 + t;
    vo[(size_t)s * 1024 + e] = f2bf(row[5120 + e]);
  }
}

// ---------------------------------------------------------------------------
// Flash attention: windowed causal + sinks. Grid (S/64, NH), block 256 (4 waves).
// ---------------------------------------------------------------------------
__global__ __launch_bounds__(256) void attn_fwd(
    const u16* __restrict__ Q, const u16* __restrict__ Kb,
    const u16* __restrict__ Vb, const float* __restrict__ sinks,
    u16* __restrict__ O)
{
  const int h   = blockIdx.y;
  const int kvh = h >> 2;            // GQA = 4
  const int q0  = blockIdx.x * 64;
  const int tid = threadIdx.x, w = tid >> 6, lane = tid & 63;
  const int ln = lane & 15, quad = lane >> 4;

  __shared__ __align__(16) u16 sQ[4][16 * 136];
  __shared__ __align__(16) u16 sK[32 * 136];
  __shared__ __align__(16) u16 sVt[128 * 48];
  __shared__ __align__(16) u16 sP[4][16 * 48];

  {
    const int qw = q0 + w * 16;
#pragma unroll
    for (int t = 0; t < 4; ++t) {
      int c = t * 64 + lane;
      int row = c >> 4, col = (c & 15) * 8;
      s8v qv = *(const s8v*)&Q[(size_t)(qw + row) * (NH * HD) + h * HD + col];
      *(s8v*)&sQ[w][row * 136 + col] = qv;
    }
  }

  const float sink = sinks[h];
  float m_r[4], l_r[4];
  f4v accO[8];
#pragma unroll
  for (int r = 0; r < 4; ++r) { m_r[r] = sink; l_r[r] = 1.0f; }
#pragma unroll
  for (int j = 0; j < 8; ++j)
#pragma unroll
    for (int r = 0; r < 4; ++r) accO[j][r] = 0.0f;

  const int kt_lo = (q0 > 1023) ? (((q0 - 1023) >> 5) << 5) : 0;
  const int kt_hi = q0 + 63;

  for (int kt = kt_lo; kt <= kt_hi; kt += 32) {
    __syncthreads();
#pragma unroll
    for (int t = 0; t < 2; ++t) {
      int c = t * 256 + tid;
      int row = c >> 4, col = (c & 15) * 8;
      size_t gbase = (size_t)(kt + row) * (NKV * HD) + kvh * HD + col;
      s8v kv = *(const s8v*)&Kb[gbase];
      *(s8v*)&sK[row * 136 + col] = kv;
      s8v vv = *(const s8v*)&Vb[gbase];
      u16* vp = (u16*)&vv;
#pragma unroll
      for (int e = 0; e < 8; ++e) sVt[(col + e) * 48 + row] = vp[e];
    }
    __syncthreads();

    f4v sc0, sc1;
#pragma unroll
    for (int r = 0; r < 4; ++r) { sc0[r] = 0.0f; sc1[r] = 0.0f; }
#pragma unroll
    for (int kb2 = 0; kb2 < 4; ++kb2) {
      s8v aq = *(const s8v*)&sQ[w][ln * 136 + kb2 * 32 + quad * 8];
      s8v b0 = *(const s8v*)&sK[ln * 136        + kb2 * 32 + quad * 8];
      s8v b1 = *(const s8v*)&sK[(16 + ln) * 136 + kb2 * 32 + quad * 8];
      sc0 = MFMA16x32(aq, b0, sc0);
      sc1 = MFMA16x32(aq, b1, sc1);
    }

    const int qrow0 = q0 + w * 16 + quad * 4;
    float p0[4], p1[4], alpha[4];
#pragma unroll
    for (int r = 0; r < 4; ++r) {
      int qi = qrow0 + r;
      int j0 = kt + ln, j1 = kt + 16 + ln;
      float s0 = ((j0 <= qi) && (qi - j0 < WINDOW)) ? sc0[r] : -1e30f;
      float s1 = ((j1 <= qi) && (qi - j1 < WINDOW)) ? sc1[r] : -1e30f;
      float mx = fmaxf(s0, s1);
#pragma unroll
      for (int d2 = 1; d2 < 16; d2 <<= 1) mx = fmaxf(mx, __shfl_xor(mx, d2));
      float mn = fmaxf(m_r[r], mx);
      alpha[r] = __expf(m_r[r] - mn);
      m_r[r] = mn;
      p0[r] = __expf(s0 - mn);
      p1[r] = __expf(s1 - mn);
      float ps = p0[r] + p1[r];
#pragma unroll
      for (int d2 = 1; d2 < 16; d2 <<= 1) ps += __shfl_xor(ps, d2);
      l_r[r] = l_r[r] * alpha[r] + ps;
    }

#pragma unroll
    for (int j = 0; j < 8; ++j)
#pragma unroll
      for (int r = 0; r < 4; ++r) accO[j][r] *= alpha[r];

#pragma unroll
    for (int r = 0; r < 4; ++r) {
      sP[w][(quad * 4 + r) * 48 + ln]      = f2bf(p0[r]);
      sP[w][(quad * 4 + r) * 48 + 16 + ln] = f2bf(p1[r]);
    }
    __syncthreads();

    s8v pf = *(const s8v*)&sP[w][ln * 48 + quad * 8];
#pragma unroll
    for (int j = 0; j < 8; ++j) {
      s8v vf = *(const s8v*)&sVt[(j * 16 + ln) * 48 + quad * 8];
      accO[j] = MFMA16x32(pf, vf, accO[j]);
    }
  }

#pragma unroll
  for (int j = 0; j < 8; ++j) {
#pragma unroll
    for (int r = 0; r < 4; ++r) {
      int row = q0 + w * 16 + quad * 4 + r;
      int col = h * HD + j * 16 + ln;
      O[(size_t)row * (NH * HD) + col] = f2bf(accO[j][r] / l_r[r]);
    }
  }
}

// ---------------------------------------------------------------------------
// Launch
// ---------------------------------------------------------------------------
extern "C" void kernel_launch(void* const* d_in, const int* in_sizes, int n_in,
                              void* d_out, int out_size, void* d_ws, size_t ws_size,
                              hipStream_t stream) {
  const float* hidden    = (const float*)d_in[0];
  const int*   positions = (const int*)d_in[1];
  const float* qkv_w     = (const float*)d_in[2];
  const float* qkv_b     = (const float*)d_in[3];
  const float* o_w       = (const float*)d_in[4];
  const float* o_b       = (const float*)d_in[5];
  const float* sinks     = (const float*)d_in[6];

  char* ws = (char*)d_ws;
  // workspace layout (bytes):
  //   qkvf : 2048*6144*4 = 50331648  (f32 qkv projection)
  //   qb   : 2048*4096*2 = 16777216  (bf16 q, rope'd, scaled)
  //   kb   : 2048*1024*2 =  4194304  (bf16 k, rope'd)
  //   vb   : 2048*1024*2 =  4194304  (bf16 v)
  //   attn : 2048*4096*2 = 16777216  (bf16 attention output)
  float* qkvf = (float*)ws;
  u16* qb   = (u16*)(ws + 50331648ull);
  u16* kb   = (u16*)(ws + 50331648ull + 16777216ull);
  u16* vb   = (u16*)(ws + 50331648ull + 16777216ull + 4194304ull);
  u16* attn = (u16*)(ws + 50331648ull + 16777216ull + 4194304ull + 4194304ull);

  gemm_t<0><<<dim3(QKV_N / 128, S_LEN / 128), 256, 0, stream>>>(
      (const void*)hidden, qkv_w, qkv_b, qkvf, S_LEN, QKV_N, HID);

  rope_split<<<S_LEN, 256, 0, stream>>>(qkvf, positions, qb, kb, vb);

  attn_fwd<<<dim3(S_LEN / 64, NH), 256, 0, stream>>>(qb, kb, vb, sinks, attn);

  gemm_t<1><<<dim3(HID / 128, S_LEN / 128), 256, 0, stream>>>(
      (const void*)attn, o_w, o_b, (float*)d_out, S_LEN, HID, HID);
}

// Round 5
// 556.921 us; speedup vs baseline: 1.3824x; 1.3824x over previous
//
#include <hip/hip_runtime.h>

#define S_LEN   2048
#define HID     4096
#define NH      32
#define NKV     8
#define HD      128
#define QKV_N   (NH*HD + 2*NKV*HD)   // 6144
#define WINDOW  1024

typedef unsigned short u16;
typedef short s8v  __attribute__((ext_vector_type(8)));
typedef short s4v  __attribute__((ext_vector_type(4)));
typedef float f4v  __attribute__((ext_vector_type(4)));

#define MFMA16x32(a, b, c) __builtin_amdgcn_mfma_f32_16x16x32_bf16(a, b, c, 0, 0, 0)

typedef __attribute__((address_space(1))) const unsigned int g_u32;
typedef __attribute__((address_space(3))) unsigned int l_u32;

__device__ __forceinline__ float bf2f(u16 h) {
  union { unsigned int u; float f; } x;
  x.u = ((unsigned int)h) << 16;
  return x.f;
}
__device__ __forceinline__ u16 f2bf(float f) {
  union { float f; unsigned int u; } x;
  x.f = f;
  unsigned int u = x.u;
  return (u16)((u + 0x7FFFu + ((u >> 16) & 1u)) >> 16);
}

// ---------------------------------------------------------------------------
// f32 -> bf16 elementwise. n multiple of 1024. grid = n/1024, block 256.
// ---------------------------------------------------------------------------
__global__ __launch_bounds__(256) void cvt_bf16(const float* __restrict__ in,
                                               u16* __restrict__ out) {
  int i = (blockIdx.x * 256 + threadIdx.x) * 4;
  float4 v = *(const float4*)&in[i];
  u16 h[4] = { f2bf(v.x), f2bf(v.y), f2bf(v.z), f2bf(v.w) };
  *(s4v*)&out[i] = *(const s4v*)h;
}

// ---------------------------------------------------------------------------
// GEMM: C[M,N] = A[M,K](bf16) * B[N,K](bf16)^T + bias[N](f32)
// OUT_BF16: C bf16, else C f32. m97 structure: 128x128 tile, BK=32,
// global_load_lds width-16 staging, mfma 16x16x32 bf16.
// ---------------------------------------------------------------------------
template<int OUT_BF16>
__global__ __launch_bounds__(256) void gemm_bt(
    const u16* __restrict__ A, const u16* __restrict__ B,
    const float* __restrict__ bias, void* __restrict__ Cp,
    int M, int N, int K)
{
  __shared__ __align__(16) u16 sA[128 * 32];
  __shared__ __align__(16) u16 sB[128 * 32];
  const int tid  = threadIdx.x;
  const int lane = tid & 63;
  const int w    = tid >> 6;
  const int wr   = w >> 1, wc = w & 1;
  const int ln   = lane & 15, quad = lane >> 4;
  const long mBase = (long)blockIdx.y * 128;
  const long nBase = (long)blockIdx.x * 128;

  f4v acc[4][4];
#pragma unroll
  for (int i = 0; i < 4; ++i)
#pragma unroll
    for (int j = 0; j < 4; ++j)
#pragma unroll
      for (int r = 0; r < 4; ++r) acc[i][j][r] = 0.0f;

  const int steps = K >> 5;
  for (int kt = 0; kt < steps; ++kt) {
    __syncthreads();
#pragma unroll
    for (int p = 0; p < 2; ++p) {
      int c = p * 256 + tid;          // 16B chunk id
      int row = c >> 2, col = (c & 3) << 3;
      const u16* ga = A + (mBase + row) * (long)K + kt * 32 + col;
      const u16* gb = B + (nBase + row) * (long)K + kt * 32 + col;
      u16* la = sA + (p * 256 + w * 64) * 8;   // wave-uniform base
      u16* lb = sB + (p * 256 + w * 64) * 8;
      __builtin_amdgcn_global_load_lds((g_u32*)(const void*)ga, (l_u32*)(void*)la, 16, 0, 0);
      __builtin_amdgcn_global_load_lds((g_u32*)(const void*)gb, (l_u32*)(void*)lb, 16, 0, 0);
    }
    __syncthreads();

    s8v af[4], bfr[4];
#pragma unroll
    for (int i = 0; i < 4; ++i)
      af[i] = *(const s8v*)&sA[(wr * 64 + i * 16 + ln) * 32 + quad * 8];
#pragma unroll
    for (int j = 0; j < 4; ++j)
      bfr[j] = *(const s8v*)&sB[(wc * 64 + j * 16 + ln) * 32 + quad * 8];
#pragma unroll
    for (int i = 0; i < 4; ++i)
#pragma unroll
      for (int j = 0; j < 4; ++j)
        acc[i][j] = MFMA16x32(af[i], bfr[j], acc[i][j]);
  }

#pragma unroll
  for (int i = 0; i < 4; ++i) {
    long rowb = mBase + wr * 64 + i * 16 + quad * 4;
#pragma unroll
    for (int j = 0; j < 4; ++j) {
      long col = nBase + wc * 64 + j * 16 + ln;
      float bv = bias[col];
#pragma unroll
      for (int r = 0; r < 4; ++r) {
        float v = acc[i][j][r] + bv;
        if (OUT_BF16) ((u16*)Cp)[(rowb + r) * (long)N + col] = f2bf(v);
        else          ((float*)Cp)[(rowb + r) * (long)N + col] = v;
      }
    }
  }
}

// ---------------------------------------------------------------------------
// RoPE (YaRN, NEOX) on bf16 qkv; SCALE folded into q. One block per position.
// ---------------------------------------------------------------------------
__global__ __launch_bounds__(256) void rope_split(
    const u16* __restrict__ qkv, const int* __restrict__ positions,
    u16* __restrict__ qo, u16* __restrict__ ko, u16* __restrict__ vo)
{
  const int s = blockIdx.x;
  const int t = threadIdx.x;
  __shared__ float csh[64], snh[64];

  if (t < 64) {
    const double LN_BASE = log(500000.0);
    const double TWO_PI  = 6.283185307179586476925287;
    double cf  = 128.0 * log(32768.0 / (32.0 * TWO_PI)) / (2.0 * LN_BASE);
    double cs_ = 128.0 * log(32768.0 / TWO_PI) / (2.0 * LN_BASE);
    double lowd  = floor(cf);  if (lowd < 0.0)  lowd = 0.0;
    double highd = ceil(cs_);  if (highd > 63.0) highd = 63.0;
    double denom = highd - lowd; if (denom < 0.001) denom = 0.001;
    double d = (double)t;
    double inv_extra = exp(-LN_BASE * d / 64.0);
    double inv_inter = inv_extra * 0.25;
    double ramp = (d - lowd) / denom;
    ramp = ramp < 0.0 ? 0.0 : (ramp > 1.0 ? 1.0 : ramp);
    double maskv = 1.0 - ramp;
    double invf = inv_inter * (1.0 - maskv) + inv_extra * maskv;
    float freq = (float)positions[s] * (float)invf;
    const float msc = 1.1386294361119891f;
    csh[t] = cosf(freq) * msc;
    snh[t] = sinf(freq) * msc;
  }
  __syncthreads();

  const u16* row = qkv + (size_t)s * QKV_N;
  const float SC = 0.08838834764831845f;      // 128^-0.5

#pragma unroll
  for (int i = 0; i < 8; ++i) {
    int p = i * 256 + t;
    int hh = p >> 6, d = p & 63;
    float x1 = bf2f(row[hh * 128 + d]), x2 = bf2f(row[hh * 128 + d + 64]);
    float c = csh[d], sn = snh[d];
    qo[(size_t)s * 4096 + hh * 128 + d]      = f2bf((x1 * c - x2 * sn) * SC);
    qo[(size_t)s * 4096 + hh * 128 + d + 64] = f2bf((x2 * c + x1 * sn) * SC);
  }
#pragma unroll
  for (int i = 0; i < 2; ++i) {
    int p = i * 256 + t;
    int hh = p >> 6, d = p & 63;
    float x1 = bf2f(row[4096 + hh * 128 + d]), x2 = bf2f(row[4096 + hh * 128 + d + 64]);
    float c = csh[d], sn = snh[d];
    ko[(size_t)s * 1024 + hh * 128 + d]      = f2bf(x1 * c - x2 * sn);
    ko[(size_t)s * 1024 + hh * 128 + d + 64] = f2bf(x2 * c + x1 * sn);
  }
#pragma unroll
  for (int i = 0; i < 4; ++i) {
    int e = i * 256 + t;
    vo[(size_t)s * 1024 + e] = row[5120 + e];   // plain copy (already bf16)
  }
}

// ---------------------------------------------------------------------------
// V transpose: vb[2048][1024] -> vt[1024][2048] (u16). 64x64 tiles via LDS.
// grid (2048/64, 1024/64) = (32, 16), block 256.
// ---------------------------------------------------------------------------
__global__ __launch_bounds__(256) void transpose_v(const u16* __restrict__ vb,
                                                   u16* __restrict__ vt) {
  __shared__ u16 tile[64][72];
  const int s0 = blockIdx.x * 64, c0 = blockIdx.y * 64;
  const int tid = threadIdx.x;
#pragma unroll
  for (int t = 0; t < 2; ++t) {
    int row = t * 32 + (tid >> 3), col = (tid & 7) * 8;
    *(s8v*)&tile[row][col] = *(const s8v*)&vb[(size_t)(s0 + row) * 1024 + c0 + col];
  }
  __syncthreads();
#pragma unroll
  for (int t = 0; t < 2; ++t) {
    int orow = t * 32 + (tid >> 3), ocol = (tid & 7) * 8;
    u16 v[8];
#pragma unroll
    for (int e = 0; e < 8; ++e) v[e] = tile[ocol + e][orow];
    *(s8v*)&vt[(size_t)(c0 + orow) * 2048 + s0 + ocol] = *(const s8v*)v;
  }
}

// ---------------------------------------------------------------------------
// Flash attention v2: transposed scores D[key][q]. Grid (S/64, NH), 4 waves.
// Q in registers (B operand). K staged [64][136], V^T staged [128][72].
// Softmax per-lane (q = ln) with only 2 cross-quad shuffles per reduction.
// FIXES vs round 3/4: (1) sK staging covered only dims 0..63 — now full 128
// (this was the NaN: uninit LDS -> NaN bf16 -> exp -> NaN). (2) barriers
// between cross-lane LDS write/read (sP->PV, sO->readback): HW DS pipe is
// in-order but compiler per-lane alias analysis may reorder without them.
// ---------------------------------------------------------------------------
__global__ __launch_bounds__(256) void attn_fwd(
    const u16* __restrict__ Q, const u16* __restrict__ Kb,
    const u16* __restrict__ Vt, const float* __restrict__ sinks,
    u16* __restrict__ O)
{
  const int h = blockIdx.y, kvh = h >> 2;
  const int q0 = blockIdx.x * 64;
  const int tid = threadIdx.x, w = tid >> 6, lane = tid & 63;
  const int ln = lane & 15, quad = lane >> 4;
  const int qw = q0 + w * 16;        // wave's first query
  const int qi = qw + ln;            // this lane's query (n-index)

  __shared__ __align__(16) u16 sK[64 * 136];
  __shared__ __align__(16) u16 sVt[128 * 72];
  __shared__ __align__(16) u16 sP[4][16 * 72];

  // Q B-fragments: lane ln = q row; k = d (quad*8+j per 32-chunk)
  s8v qf[4];
  {
    const u16* qrow = Q + (size_t)qi * 4096 + h * 128;
#pragma unroll
    for (int kb = 0; kb < 4; ++kb)
      qf[kb] = *(const s8v*)&qrow[kb * 32 + quad * 8];
  }

  float m_v = sinks[h], l_v = 1.0f;
  f4v accO[8];
#pragma unroll
  for (int j = 0; j < 8; ++j)
#pragma unroll
    for (int r = 0; r < 4; ++r) accO[j][r] = 0.0f;

  int lo = q0 - (WINDOW - 1); if (lo < 0) lo = 0; lo &= ~63;

  for (int kt = lo; kt <= q0; kt += 64) {
    __syncthreads();
    // stage K tile: 64 keys x 128 dims, stride 136  (1024 chunks of 8 u16)
#pragma unroll
    for (int t = 0; t < 4; ++t) {
      int c = t * 256 + tid;
      int row = c >> 4, col = (c & 15) * 8;
      *(s8v*)&sK[row * 136 + col] =
          *(const s8v*)&Kb[(size_t)(kt + row) * 1024 + kvh * 128 + col];
    }
    // stage V^T tile: 128 dims x 64 keys, stride 72 (1024 chunks of 8 u16)
#pragma unroll
    for (int t = 0; t < 4; ++t) {
      int c = t * 256 + tid;
      int row = c >> 3, col = (c & 7) * 8;
      *(s8v*)&sVt[row * 72 + col] =
          *(const s8v*)&Vt[(size_t)(kvh * 128 + row) * 2048 + kt + col];
    }
    __syncthreads();

    // scores^T for 4 half-tiles of 16 keys: element (key=quad*4+r, q=ln)
    f4v sc[4];
    bool dead[4];
#pragma unroll
    for (int h4 = 0; h4 < 4; ++h4) {
      const int kb16 = kt + h4 * 16;
      dead[h4] = (kb16 > qw + 15) || (kb16 + 15 < qw - (WINDOW - 1));
      if (dead[h4]) {
#pragma unroll
        for (int r = 0; r < 4; ++r) sc[h4][r] = -1e30f;
        continue;
      }
      f4v s;
#pragma unroll
      for (int r = 0; r < 4; ++r) s[r] = 0.0f;
#pragma unroll
      for (int kb = 0; kb < 4; ++kb) {
        s8v kf = *(const s8v*)&sK[(h4 * 16 + ln) * 136 + kb * 32 + quad * 8];
        s = MFMA16x32(kf, qf[kb], s);   // A=K rows (m=key), B=Q (n=q)
      }
      const bool full = (kb16 + 15 <= qw) && (qw + 15 - kb16 <= WINDOW - 1);
      if (!full) {
        int base = qi - kb16 - quad * 4;   // qi - key for r=0
#pragma unroll
        for (int r = 0; r < 4; ++r)
          s[r] = ((unsigned)(base - r) <= (WINDOW - 1)) ? s[r] : -1e30f;
      }
      sc[h4] = s;
    }

    // online softmax: per-lane column q=ln; reduce 16 in-lane + 2 shfl
    float mn = m_v;
#pragma unroll
    for (int h4 = 0; h4 < 4; ++h4)
#pragma unroll
      for (int r = 0; r < 4; ++r) mn = fmaxf(mn, sc[h4][r]);
    mn = fmaxf(mn, __shfl_xor(mn, 16));
    mn = fmaxf(mn, __shfl_xor(mn, 32));

    float alpha = __expf(m_v - mn);
    m_v = mn;
    l_v *= alpha;
#pragma unroll
    for (int j = 0; j < 8; ++j)
#pragma unroll
      for (int r = 0; r < 4; ++r) accO[j][r] *= alpha;

    float lsum = 0.0f;
#pragma unroll
    for (int h4 = 0; h4 < 4; ++h4) {
      float p[4];
#pragma unroll
      for (int r = 0; r < 4; ++r) p[r] = __expf(sc[h4][r] - mn);
      lsum += (p[0] + p[1]) + (p[2] + p[3]);
      u16 pb[4] = { f2bf(p[0]), f2bf(p[1]), f2bf(p[2]), f2bf(p[3]) };
      *(s4v*)&sP[w][ln * 72 + h4 * 16 + quad * 4] = *(const s4v*)pb;
    }
    lsum += __shfl_xor(lsum, 16);
    lsum += __shfl_xor(lsum, 32);
    l_v += lsum;

    __syncthreads();   // cross-lane sP visibility (compiler ordering)

    // PV: A = V^T rows (m=d), B = P (n=q), k = 32-key chunks
#pragma unroll
    for (int c2 = 0; c2 < 2; ++c2) {
      if (dead[2 * c2] && dead[2 * c2 + 1]) continue;
      s8v pf = *(const s8v*)&sP[w][ln * 72 + c2 * 32 + quad * 8];
#pragma unroll
      for (int j = 0; j < 8; ++j) {
        s8v vf = *(const s8v*)&sVt[(j * 16 + ln) * 72 + c2 * 32 + quad * 8];
        accO[j] = MFMA16x32(vf, pf, accO[j]);
      }
    }
  }

  // epilogue: O^T (d rows, q cols) -> LDS transpose -> coalesced store
  __syncthreads();                    // all waves done with sK/sVt
  u16* sO = sK;                       // reuse: [64 q-rows][136]
  const float rl = 1.0f / l_v;
#pragma unroll
  for (int j = 0; j < 8; ++j) {
    u16 ob[4] = { f2bf(accO[j][0] * rl), f2bf(accO[j][1] * rl),
                  f2bf(accO[j][2] * rl), f2bf(accO[j][3] * rl) };
    *(s4v*)&sO[(w * 16 + ln) * 136 + j * 16 + quad * 4] = *(const s4v*)ob;
  }
  __syncthreads();                    // cross-lane sO visibility
  {
    int row = lane >> 2, cc = lane & 3;
#pragma unroll
    for (int i = 0; i < 4; ++i) {
      s8v v = *(const s8v*)&sO[(w * 16 + row) * 136 + cc * 8 + i * 32];
      *(s8v*)&O[(size_t)(q0 + w * 16 + row) * 4096 + h * 128 + cc * 8 + i * 32] = v;
    }
  }
}

// ---------------------------------------------------------------------------
// Launch. Workspace peak = 92,274,688 B (round-2 proven footprint).
// Phase-aliased layout:
//   Region X [0, 48 MB):       qkv_w bf16 (dies after gemm1)
//                              -> qb@0 kb@16M vb@20M vt@24M attn@28M (45 MB)
//   Region Y [48 MB, 88 MB):   hidden bf16 @48M + qkvb @64M (dies after rope)
//                              -> o_w bf16 @48M (32 MB)
// ---------------------------------------------------------------------------
extern "C" void kernel_launch(void* const* d_in, const int* in_sizes, int n_in,
                              void* d_out, int out_size, void* d_ws, size_t ws_size,
                              hipStream_t stream) {
  const float* hidden    = (const float*)d_in[0];
  const int*   positions = (const int*)d_in[1];
  const float* qkv_w     = (const float*)d_in[2];
  const float* qkv_b     = (const float*)d_in[3];
  const float* o_w       = (const float*)d_in[4];
  const float* o_b       = (const float*)d_in[5];
  const float* sinks     = (const float*)d_in[6];

  char* ws = (char*)d_ws;
  // Region X
  u16* wW   = (u16*)ws;                         // 48 MB (phase A)
  u16* qb   = (u16*)ws;                         // 16 MB (phase B)
  u16* kb   = (u16*)(ws + 16777216ull);         //  4 MB
  u16* vb   = (u16*)(ws + 20971520ull);         //  4 MB
  u16* vt   = (u16*)(ws + 25165824ull);         //  4 MB
  u16* attn = (u16*)(ws + 29360128ull);         // 16 MB (ends 45 MB)
  // Region Y
  u16* hb   = (u16*)(ws + 50331648ull);         // 16 MB (phase A)
  u16* qkvb = (u16*)(ws + 67108864ull);         // 24 MB (ends 92,274,688)
  u16* oWb  = (u16*)(ws + 50331648ull);         // 32 MB (phase B, ends 84 MB)

  cvt_bf16<<<8192, 256, 0, stream>>>(hidden, hb);       // 2048*4096
  cvt_bf16<<<24576, 256, 0, stream>>>(qkv_w, wW);       // 6144*4096

  gemm_bt<1><<<dim3(QKV_N / 128, S_LEN / 128), 256, 0, stream>>>(
      hb, wW, qkv_b, (void*)qkvb, S_LEN, QKV_N, HID);   // wW, hb die here

  rope_split<<<S_LEN, 256, 0, stream>>>(qkvb, positions, qb, kb, vb); // qkvb dies

  cvt_bf16<<<16384, 256, 0, stream>>>(o_w, oWb);        // 4096*4096, region Y reuse

  transpose_v<<<dim3(32, 16), 256, 0, stream>>>(vb, vt);

  attn_fwd<<<dim3(S_LEN / 64, NH), 256, 0, stream>>>(qb, kb, vt, sinks, attn);

  gemm_bt<0><<<dim3(HID / 128, S_LEN / 128), 256, 0, stream>>>(
      attn, oWb, o_b, d_out, S_LEN, HID, HID);
}